// Round 3
// baseline (506.937 us; speedup 1.0000x reference)
//
#include <hip/hip_runtime.h>

#define BB 4
#define SS 2048
#define EE 512
#define HH 8
#define DKK 64
#define MM (BB*SS)

typedef unsigned short u16;
typedef unsigned int u32;
typedef __attribute__((ext_vector_type(8))) short short8;
typedef __attribute__((ext_vector_type(4))) short short4v;
typedef __attribute__((ext_vector_type(4))) float f32x4;

__device__ inline u16 f2bf(float f) {            // RNE f32 -> bf16
  union { float f; u32 u; } v; v.f = f;
  u32 r = v.u + 0x7fff + ((v.u >> 16) & 1);
  return (u16)(r >> 16);
}
__device__ inline float bf2f(u16 u) {
  union { u32 u; float f; } v; v.u = ((u32)u) << 16;
  return v.f;
}
// hi = RNE bf16, lo = RNE bf16 of residual (covers ~16 mantissa bits total)
__device__ inline void split2(float f, u16 &h, u16 &l) {
  h = f2bf(f);
  l = f2bf(f - bf2f(h));
}

// ---------- Projection GEMM: C[m,n] = sum_k A[m,k]*W[n,k] + bias[n] ----------
// A: [M,512] f32. W: [512,512] f32 (row n holds W[n,:]). bias f32.
// COMP=1: 3-term compensated MFMA, writes bf16 hi+lo (for Q,K).
// COMP=0: plain 1-term bf16 MFMA, writes bf16 hi only (for V).
template<int COMP>
__global__ __launch_bounds__(256) void proj(
    const float* __restrict__ A, const float* __restrict__ W,
    const float* __restrict__ bias, u16* __restrict__ Chi, u16* __restrict__ Clo)
{
  __shared__ __align__(16) u16 Ah[128][72];
  __shared__ __align__(16) u16 Al[COMP ? 128 : 1][72];
  __shared__ __align__(16) u16 Bh[64][72];
  __shared__ __align__(16) u16 Bl[COMP ? 64 : 1][72];
  const int m0 = blockIdx.x * 128, n0 = blockIdx.y * 64;
  const int tid = threadIdx.x, w = tid >> 6, l = tid & 63;
  const int row = l & 15, kq = (l >> 4) * 8;
  f32x4 acc[2][4];
  #pragma unroll
  for (int i = 0; i < 2; ++i)
    #pragma unroll
    for (int j = 0; j < 4; ++j) acc[i][j] = (f32x4){0.f, 0.f, 0.f, 0.f};

  for (int k0 = 0; k0 < 512; k0 += 64) {
    __syncthreads();
    #pragma unroll
    for (int i = 0; i < 8; ++i) {            // A tile: 128 x 64 f32
      int u = tid + i * 256; int r = u >> 4, c4 = (u & 15) * 4;
      f32x4 v = *(const f32x4*)&A[(size_t)(m0 + r) * 512 + k0 + c4];
      u16 h[4], lo[4];
      #pragma unroll
      for (int j = 0; j < 4; ++j) split2(v[j], h[j], lo[j]);
      *(short4v*)&Ah[r][c4] = (short4v){(short)h[0], (short)h[1], (short)h[2], (short)h[3]};
      if (COMP)
        *(short4v*)&Al[r][c4] = (short4v){(short)lo[0], (short)lo[1], (short)lo[2], (short)lo[3]};
    }
    #pragma unroll
    for (int i = 0; i < 4; ++i) {            // W tile: 64 x 64 f32
      int u = tid + i * 256; int r = u >> 4, c4 = (u & 15) * 4;
      f32x4 v = *(const f32x4*)&W[(size_t)(n0 + r) * 512 + k0 + c4];
      u16 h[4], lo[4];
      #pragma unroll
      for (int j = 0; j < 4; ++j) split2(v[j], h[j], lo[j]);
      *(short4v*)&Bh[r][c4] = (short4v){(short)h[0], (short)h[1], (short)h[2], (short)h[3]};
      if (COMP)
        *(short4v*)&Bl[r][c4] = (short4v){(short)lo[0], (short)lo[1], (short)lo[2], (short)lo[3]};
    }
    __syncthreads();
    short8 ah[2][2], al[2][2], bh[4][2], bl[4][2];
    #pragma unroll
    for (int mf = 0; mf < 2; ++mf)
      #pragma unroll
      for (int ks = 0; ks < 2; ++ks) {
        ah[mf][ks] = *(const short8*)&Ah[w * 32 + mf * 16 + row][ks * 32 + kq];
        if (COMP) al[mf][ks] = *(const short8*)&Al[w * 32 + mf * 16 + row][ks * 32 + kq];
      }
    #pragma unroll
    for (int nf = 0; nf < 4; ++nf)
      #pragma unroll
      for (int ks = 0; ks < 2; ++ks) {
        bh[nf][ks] = *(const short8*)&Bh[nf * 16 + row][ks * 32 + kq];
        if (COMP) bl[nf][ks] = *(const short8*)&Bl[nf * 16 + row][ks * 32 + kq];
      }
    #pragma unroll
    for (int mf = 0; mf < 2; ++mf)
      #pragma unroll
      for (int nf = 0; nf < 4; ++nf)
        #pragma unroll
        for (int ks = 0; ks < 2; ++ks) {
          acc[mf][nf] = __builtin_amdgcn_mfma_f32_16x16x32_bf16(
              ah[mf][ks], bh[nf][ks], acc[mf][nf], 0, 0, 0);
          if (COMP) {
            acc[mf][nf] = __builtin_amdgcn_mfma_f32_16x16x32_bf16(
                ah[mf][ks], bl[nf][ks], acc[mf][nf], 0, 0, 0);
            acc[mf][nf] = __builtin_amdgcn_mfma_f32_16x16x32_bf16(
                al[mf][ks], bh[nf][ks], acc[mf][nf], 0, 0, 0);
          }
        }
  }
  // C layout: col = l&15, row = (l>>4)*4 + reg
  #pragma unroll
  for (int mf = 0; mf < 2; ++mf)
    #pragma unroll
    for (int nf = 0; nf < 4; ++nf)
      #pragma unroll
      for (int r = 0; r < 4; ++r) {
        int m = m0 + w * 32 + mf * 16 + ((l >> 4) << 2) + r;
        int n = n0 + nf * 16 + (l & 15);
        float c = acc[mf][nf][r] + bias[n];
        size_t idx = (size_t)m * 512 + n;
        if (COMP) { u16 h, lo; split2(c, h, lo); Chi[idx] = h; Clo[idx] = lo; }
        else Chi[idx] = f2bf(c);
      }
}

// ---------- Output GEMM: out[m,n] = sum_k X[m,k]*Wo[n,k] + bo[n], f32 out ----------
__global__ __launch_bounds__(256) void gemm_out(
    const u16* __restrict__ A, const float* __restrict__ W,
    const float* __restrict__ bias, float* __restrict__ C)
{
  __shared__ __align__(16) u16 As[128][72];
  __shared__ __align__(16) u16 Bs[64][72];
  const int m0 = blockIdx.x * 128, n0 = blockIdx.y * 64;
  const int tid = threadIdx.x, w = tid >> 6, l = tid & 63;
  const int row = l & 15, kq = (l >> 4) * 8;
  f32x4 acc[2][4];
  #pragma unroll
  for (int i = 0; i < 2; ++i)
    #pragma unroll
    for (int j = 0; j < 4; ++j) acc[i][j] = (f32x4){0.f, 0.f, 0.f, 0.f};

  for (int k0 = 0; k0 < 512; k0 += 64) {
    __syncthreads();
    #pragma unroll
    for (int i = 0; i < 4; ++i) {            // X tile bf16: 128 x 64
      int u = tid + i * 256; int r = u >> 3, c = (u & 7) * 8;
      *(short8*)&As[r][c] = *(const short8*)&A[(size_t)(m0 + r) * 512 + k0 + c];
    }
    #pragma unroll
    for (int i = 0; i < 4; ++i) {            // Wo tile f32 -> bf16 hi
      int u = tid + i * 256; int r = u >> 4, c4 = (u & 15) * 4;
      f32x4 v = *(const f32x4*)&W[(size_t)(n0 + r) * 512 + k0 + c4];
      *(short4v*)&Bs[r][c4] = (short4v){(short)f2bf(v[0]), (short)f2bf(v[1]),
                                        (short)f2bf(v[2]), (short)f2bf(v[3])};
    }
    __syncthreads();
    short8 a[2][2], bfr[4][2];
    #pragma unroll
    for (int mf = 0; mf < 2; ++mf)
      #pragma unroll
      for (int ks = 0; ks < 2; ++ks)
        a[mf][ks] = *(const short8*)&As[w * 32 + mf * 16 + row][ks * 32 + kq];
    #pragma unroll
    for (int nf = 0; nf < 4; ++nf)
      #pragma unroll
      for (int ks = 0; ks < 2; ++ks)
        bfr[nf][ks] = *(const short8*)&Bs[nf * 16 + row][ks * 32 + kq];
    #pragma unroll
    for (int mf = 0; mf < 2; ++mf)
      #pragma unroll
      for (int nf = 0; nf < 4; ++nf)
        #pragma unroll
        for (int ks = 0; ks < 2; ++ks)
          acc[mf][nf] = __builtin_amdgcn_mfma_f32_16x16x32_bf16(
              a[mf][ks], bfr[nf][ks], acc[mf][nf], 0, 0, 0);
  }
  #pragma unroll
  for (int mf = 0; mf < 2; ++mf)
    #pragma unroll
    for (int nf = 0; nf < 4; ++nf)
      #pragma unroll
      for (int r = 0; r < 4; ++r) {
        int m = m0 + w * 32 + mf * 16 + ((l >> 4) << 2) + r;
        int n = n0 + nf * 16 + (l & 15);
        C[(size_t)m * 512 + n] = acc[mf][nf][r] + bias[n];
      }
}

// ---------- Flash attention per (b, h, 64-row q-tile); 4 waves x 16 q-rows ----------
// Scores = (Q.K^T)*8, compensated; mask==0 -> -1e9; online softmax; PV in bf16.
// Output store folds in the reference's no-transpose reshape quirk.
__global__ __launch_bounds__(256) void attn(
    const u16* __restrict__ Qhi, const u16* __restrict__ Qlo,
    const u16* __restrict__ Khi, const u16* __restrict__ Klo,
    const u16* __restrict__ V, const int* __restrict__ mask,
    u16* __restrict__ X)
{
  __shared__ __align__(16) u16 KhiS[64][72];
  __shared__ __align__(16) u16 KloS[64][72];
  __shared__ __align__(16) u16 VtS[64][72];   // V transposed: VtS[d][t]
  __shared__ __align__(16) u16 Pl[64][72];    // P tile, per-wave 16-row slices
  const int b = blockIdx.z, h = blockIdx.y, q0 = blockIdx.x * 64;
  const int tid = threadIdx.x, w = tid >> 6, l = tid & 63;
  const int row = l & 15, kq = (l >> 4) * 8;

  const size_t qbase = ((size_t)(b * SS) + q0 + w * 16 + row) * EE + h * DKK;
  short8 qh[2], ql[2];
  #pragma unroll
  for (int ks = 0; ks < 2; ++ks) {
    qh[ks] = *(const short8*)&Qhi[qbase + ks * 32 + kq];
    ql[ks] = *(const short8*)&Qlo[qbase + ks * 32 + kq];
  }

  float mrow[4], lrow[4];
  f32x4 acco[4];
  #pragma unroll
  for (int r = 0; r < 4; ++r) { mrow[r] = -INFINITY; lrow[r] = 0.f; }
  #pragma unroll
  for (int f = 0; f < 4; ++f) acco[f] = (f32x4){0.f, 0.f, 0.f, 0.f};

  for (int t0 = 0; t0 < SS; t0 += 64) {
    __syncthreads();
    #pragma unroll
    for (int i = 0; i < 2; ++i) {            // stage K hi/lo + transposed V
      int u = tid + i * 256; int r = u >> 3, c0 = (u & 7) * 8;
      size_t g = ((size_t)(b * SS) + t0 + r) * EE + h * DKK + c0;
      short8 hv = *(const short8*)&Khi[g];
      short8 lv = *(const short8*)&Klo[g];
      short8 vv = *(const short8*)&V[g];
      *(short8*)&KhiS[r][c0] = hv;
      *(short8*)&KloS[r][c0] = lv;
      #pragma unroll
      for (int j = 0; j < 8; ++j) VtS[c0 + j][r] = (u16)vv[j];
    }
    __syncthreads();

    f32x4 sacc[4];
    #pragma unroll
    for (int f = 0; f < 4; ++f) sacc[f] = (f32x4){0.f, 0.f, 0.f, 0.f};
    #pragma unroll
    for (int f = 0; f < 4; ++f)
      #pragma unroll
      for (int ks = 0; ks < 2; ++ks) {
        short8 kh = *(const short8*)&KhiS[f * 16 + row][ks * 32 + kq];
        short8 kl = *(const short8*)&KloS[f * 16 + row][ks * 32 + kq];
        sacc[f] = __builtin_amdgcn_mfma_f32_16x16x32_bf16(qh[ks], kh, sacc[f], 0, 0, 0);
        sacc[f] = __builtin_amdgcn_mfma_f32_16x16x32_bf16(qh[ks], kl, sacc[f], 0, 0, 0);
        sacc[f] = __builtin_amdgcn_mfma_f32_16x16x32_bf16(ql[ks], kh, sacc[f], 0, 0, 0);
      }

    const int qr0 = q0 + w * 16 + ((l >> 4) << 2);
    float sval[4][4];
    #pragma unroll
    for (int f = 0; f < 4; ++f) {
      int t = t0 + f * 16 + (l & 15);
      #pragma unroll
      for (int r = 0; r < 4; ++r) {
        int mk = mask[((size_t)(b * SS) + qr0 + r) * SS + t];
        sval[f][r] = mk ? sacc[f][r] * 8.0f : -1e9f;
      }
    }
    #pragma unroll
    for (int r = 0; r < 4; ++r) {
      float mx = fmaxf(fmaxf(sval[0][r], sval[1][r]), fmaxf(sval[2][r], sval[3][r]));
      #pragma unroll
      for (int off = 1; off < 16; off <<= 1) mx = fmaxf(mx, __shfl_xor(mx, off));
      float mnew = fmaxf(mrow[r], mx);
      float alpha = expf(mrow[r] - mnew);     // expf(-inf)=0 on first tile
      float rs = 0.f;
      #pragma unroll
      for (int f = 0; f < 4; ++f) {
        float p = expf(sval[f][r] - mnew);
        sval[f][r] = p; rs += p;
      }
      #pragma unroll
      for (int off = 1; off < 16; off <<= 1) rs += __shfl_xor(rs, off);
      lrow[r] = lrow[r] * alpha + rs;
      mrow[r] = mnew;
      #pragma unroll
      for (int f = 0; f < 4; ++f) acco[f][r] *= alpha;
    }

    // P (C layout) -> LDS -> A-frag reads; per-wave 16-row slice, same-wave dep only.
    #pragma unroll
    for (int f = 0; f < 4; ++f)
      #pragma unroll
      for (int r = 0; r < 4; ++r)
        Pl[w * 16 + ((l >> 4) << 2) + r][f * 16 + (l & 15)] = f2bf(sval[f][r]);

    #pragma unroll
    for (int f2 = 0; f2 < 4; ++f2)
      #pragma unroll
      for (int ks = 0; ks < 2; ++ks) {
        short8 p = *(const short8*)&Pl[w * 16 + row][ks * 32 + kq];
        short8 vvf = *(const short8*)&VtS[f2 * 16 + row][ks * 32 + kq];
        acco[f2] = __builtin_amdgcn_mfma_f32_16x16x32_bf16(p, vvf, acco[f2], 0, 0, 0);
      }
  }

  // X[b][h*256 + q>>3][(q&7)*64 + d]  (reference reshape quirk)
  #pragma unroll
  for (int f2 = 0; f2 < 4; ++f2)
    #pragma unroll
    for (int r = 0; r < 4; ++r) {
      int q = q0 + w * 16 + ((l >> 4) << 2) + r;
      int d = f2 * 16 + (l & 15);
      float o = acco[f2][r] / lrow[r];
      int sp = h * 256 + (q >> 3);
      int ep = ((q & 7) << 6) + d;
      X[((size_t)(b * SS) + sp) * EE + ep] = f2bf(o);
    }
}

extern "C" void kernel_launch(void* const* d_in, const int* in_sizes, int n_in,
                              void* d_out, int out_size, void* d_ws, size_t ws_size,
                              hipStream_t stream) {
  const float* query  = (const float*)d_in[0];   // all float tensors are f32 (ref dtype)
  const float* key_in = (const float*)d_in[1];
  const float* value  = (const float*)d_in[2];
  const int*   mask   = (const int*)d_in[3];
  const float* Wq = (const float*)d_in[4];
  const float* bq = (const float*)d_in[5];
  const float* Wk = (const float*)d_in[6];
  const float* bk = (const float*)d_in[7];
  const float* Wv = (const float*)d_in[8];
  const float* bv = (const float*)d_in[9];
  const float* Wo = (const float*)d_in[10];
  const float* bo = (const float*)d_in[11];

  u16* ws = (u16*)d_ws;
  const size_t NE = (size_t)MM * EE;  // 4.19M elems per [M,E] bf16 buffer
  u16* Qhi = ws;
  u16* Qlo = ws + NE;
  u16* Khi = ws + 2 * NE;
  u16* Klo = ws + 3 * NE;
  u16* Vp  = ws + 4 * NE;
  u16* X   = ws + 5 * NE;

  dim3 gblk(MM / 128, EE / 64);  // 64 x 8
  proj<1><<<gblk, 256, 0, stream>>>(query,  Wq, bq, Qhi, Qlo);
  proj<1><<<gblk, 256, 0, stream>>>(key_in, Wk, bk, Khi, Klo);
  proj<0><<<gblk, 256, 0, stream>>>(value,  Wv, bv, Vp, nullptr);
  attn<<<dim3(SS / 64, HH, BB), 256, 0, stream>>>(Qhi, Qlo, Khi, Klo, Vp, mask, X);
  gemm_out<<<gblk, 256, 0, stream>>>(X, Wo, bo, (float*)d_out);
}

// Round 4
// 437.616 us; speedup vs baseline: 1.1584x; 1.1584x over previous
//
#include <hip/hip_runtime.h>

#define BB 4
#define SS 2048
#define EE 512
#define HH 8
#define DKK 64
#define MM (BB*SS)

typedef unsigned short u16;
typedef unsigned int u32;
typedef unsigned long long u64;
typedef __attribute__((ext_vector_type(8))) short short8;
typedef __attribute__((ext_vector_type(4))) short short4v;
typedef __attribute__((ext_vector_type(4))) float f32x4;

__device__ inline u16 f2bf(float f) {            // RNE f32 -> bf16
  union { float f; u32 u; } v; v.f = f;
  u32 r = v.u + 0x7fff + ((v.u >> 16) & 1);
  return (u16)(r >> 16);
}
__device__ inline float bf2f(u16 u) {
  union { u32 u; float f; } v; v.u = ((u32)u) << 16;
  return v.f;
}
__device__ inline void split2(float f, u16 &h, u16 &l) {
  h = f2bf(f);
  l = f2bf(f - bf2f(h));
}

// ---------- mask [B,S,S] int32 -> bitmask [B*S][32] u64 (bit t&63 of word t>>6) ----------
__global__ __launch_bounds__(256) void maskpack(const int* __restrict__ mask,
                                                u64* __restrict__ mb) {
  const int bq = blockIdx.x;              // 0..B*S-1
  const int w = threadIdx.x >> 6, l = threadIdx.x & 63;
  const int* src = mask + (size_t)bq * SS;
  #pragma unroll
  for (int it = 0; it < 8; ++it) {
    int tb = it * 4 + w;                  // 0..31
    int m = src[tb * 64 + l];
    u64 bits = __ballot(m != 0);
    if (l == 0) mb[(size_t)bq * 32 + tb] = bits;
  }
}

// ---------- Projection GEMM: C[m,n] = (sum_k A[m,k]*W[n,k] + bias[n]) * cscale ----------
template<int COMP>
__global__ __launch_bounds__(256) void proj(
    const float* __restrict__ A, const float* __restrict__ W,
    const float* __restrict__ bias, u16* __restrict__ Chi, u16* __restrict__ Clo,
    float cscale)
{
  __shared__ __align__(16) u16 Ah[128][72];
  __shared__ __align__(16) u16 Al[COMP ? 128 : 1][72];
  __shared__ __align__(16) u16 Bh[64][72];
  __shared__ __align__(16) u16 Bl[COMP ? 64 : 1][72];
  const int m0 = blockIdx.x * 128, n0 = blockIdx.y * 64;
  const int tid = threadIdx.x, w = tid >> 6, l = tid & 63;
  const int row = l & 15, kq = (l >> 4) * 8;
  f32x4 acc[2][4];
  #pragma unroll
  for (int i = 0; i < 2; ++i)
    #pragma unroll
    for (int j = 0; j < 4; ++j) acc[i][j] = (f32x4){0.f, 0.f, 0.f, 0.f};

  for (int k0 = 0; k0 < 512; k0 += 64) {
    __syncthreads();
    #pragma unroll
    for (int i = 0; i < 8; ++i) {
      int u = tid + i * 256; int r = u >> 4, c4 = (u & 15) * 4;
      f32x4 v = *(const f32x4*)&A[(size_t)(m0 + r) * 512 + k0 + c4];
      u16 h[4], lo[4];
      #pragma unroll
      for (int j = 0; j < 4; ++j) split2(v[j], h[j], lo[j]);
      *(short4v*)&Ah[r][c4] = (short4v){(short)h[0], (short)h[1], (short)h[2], (short)h[3]};
      if (COMP)
        *(short4v*)&Al[r][c4] = (short4v){(short)lo[0], (short)lo[1], (short)lo[2], (short)lo[3]};
    }
    #pragma unroll
    for (int i = 0; i < 4; ++i) {
      int u = tid + i * 256; int r = u >> 4, c4 = (u & 15) * 4;
      f32x4 v = *(const f32x4*)&W[(size_t)(n0 + r) * 512 + k0 + c4];
      u16 h[4], lo[4];
      #pragma unroll
      for (int j = 0; j < 4; ++j) split2(v[j], h[j], lo[j]);
      *(short4v*)&Bh[r][c4] = (short4v){(short)h[0], (short)h[1], (short)h[2], (short)h[3]};
      if (COMP)
        *(short4v*)&Bl[r][c4] = (short4v){(short)lo[0], (short)lo[1], (short)lo[2], (short)lo[3]};
    }
    __syncthreads();
    short8 ah[2][2], al[2][2], bh[4][2], bl[4][2];
    #pragma unroll
    for (int mf = 0; mf < 2; ++mf)
      #pragma unroll
      for (int ks = 0; ks < 2; ++ks) {
        ah[mf][ks] = *(const short8*)&Ah[w * 32 + mf * 16 + row][ks * 32 + kq];
        if (COMP) al[mf][ks] = *(const short8*)&Al[w * 32 + mf * 16 + row][ks * 32 + kq];
      }
    #pragma unroll
    for (int nf = 0; nf < 4; ++nf)
      #pragma unroll
      for (int ks = 0; ks < 2; ++ks) {
        bh[nf][ks] = *(const short8*)&Bh[nf * 16 + row][ks * 32 + kq];
        if (COMP) bl[nf][ks] = *(const short8*)&Bl[nf * 16 + row][ks * 32 + kq];
      }
    #pragma unroll
    for (int mf = 0; mf < 2; ++mf)
      #pragma unroll
      for (int nf = 0; nf < 4; ++nf)
        #pragma unroll
        for (int ks = 0; ks < 2; ++ks) {
          acc[mf][nf] = __builtin_amdgcn_mfma_f32_16x16x32_bf16(
              ah[mf][ks], bh[nf][ks], acc[mf][nf], 0, 0, 0);
          if (COMP) {
            acc[mf][nf] = __builtin_amdgcn_mfma_f32_16x16x32_bf16(
                ah[mf][ks], bl[nf][ks], acc[mf][nf], 0, 0, 0);
            acc[mf][nf] = __builtin_amdgcn_mfma_f32_16x16x32_bf16(
                al[mf][ks], bh[nf][ks], acc[mf][nf], 0, 0, 0);
          }
        }
  }
  #pragma unroll
  for (int mf = 0; mf < 2; ++mf)
    #pragma unroll
    for (int nf = 0; nf < 4; ++nf)
      #pragma unroll
      for (int r = 0; r < 4; ++r) {
        int m = m0 + w * 32 + mf * 16 + ((l >> 4) << 2) + r;
        int n = n0 + nf * 16 + (l & 15);
        float c = (acc[mf][nf][r] + bias[n]) * cscale;
        size_t idx = (size_t)m * 512 + n;
        if (COMP) { u16 h, lo; split2(c, h, lo); Chi[idx] = h; Clo[idx] = lo; }
        else Chi[idx] = f2bf(c);
      }
}

// ---------- Output GEMM: out[m,n] = sum_k X[m,k]*Wo[n,k] + bo[n], f32 out ----------
__global__ __launch_bounds__(256) void gemm_out(
    const u16* __restrict__ A, const float* __restrict__ W,
    const float* __restrict__ bias, float* __restrict__ C)
{
  __shared__ __align__(16) u16 As[128][72];
  __shared__ __align__(16) u16 Bs[64][72];
  const int m0 = blockIdx.x * 128, n0 = blockIdx.y * 64;
  const int tid = threadIdx.x, w = tid >> 6, l = tid & 63;
  const int row = l & 15, kq = (l >> 4) * 8;
  f32x4 acc[2][4];
  #pragma unroll
  for (int i = 0; i < 2; ++i)
    #pragma unroll
    for (int j = 0; j < 4; ++j) acc[i][j] = (f32x4){0.f, 0.f, 0.f, 0.f};

  for (int k0 = 0; k0 < 512; k0 += 64) {
    __syncthreads();
    #pragma unroll
    for (int i = 0; i < 4; ++i) {
      int u = tid + i * 256; int r = u >> 3, c = (u & 7) * 8;
      *(short8*)&As[r][c] = *(const short8*)&A[(size_t)(m0 + r) * 512 + k0 + c];
    }
    #pragma unroll
    for (int i = 0; i < 4; ++i) {
      int u = tid + i * 256; int r = u >> 4, c4 = (u & 15) * 4;
      f32x4 v = *(const f32x4*)&W[(size_t)(n0 + r) * 512 + k0 + c4];
      *(short4v*)&Bs[r][c4] = (short4v){(short)f2bf(v[0]), (short)f2bf(v[1]),
                                        (short)f2bf(v[2]), (short)f2bf(v[3])};
    }
    __syncthreads();
    short8 a[2][2], bfr[4][2];
    #pragma unroll
    for (int mf = 0; mf < 2; ++mf)
      #pragma unroll
      for (int ks = 0; ks < 2; ++ks)
        a[mf][ks] = *(const short8*)&As[w * 32 + mf * 16 + row][ks * 32 + kq];
    #pragma unroll
    for (int nf = 0; nf < 4; ++nf)
      #pragma unroll
      for (int ks = 0; ks < 2; ++ks)
        bfr[nf][ks] = *(const short8*)&Bs[nf * 16 + row][ks * 32 + kq];
    #pragma unroll
    for (int mf = 0; mf < 2; ++mf)
      #pragma unroll
      for (int nf = 0; nf < 4; ++nf)
        #pragma unroll
        for (int ks = 0; ks < 2; ++ks)
          acc[mf][nf] = __builtin_amdgcn_mfma_f32_16x16x32_bf16(
              a[mf][ks], bfr[nf][ks], acc[mf][nf], 0, 0, 0);
  }
  #pragma unroll
  for (int mf = 0; mf < 2; ++mf)
    #pragma unroll
    for (int nf = 0; nf < 4; ++nf)
      #pragma unroll
      for (int r = 0; r < 4; ++r) {
        int m = m0 + w * 32 + mf * 16 + ((l >> 4) << 2) + r;
        int n = n0 + nf * 16 + (l & 15);
        C[(size_t)m * 512 + n] = acc[mf][nf][r] + bias[n];
      }
}

// ---------- Flash attention; Q prescaled by 8; mask from 2MB bitmask ----------
// LDS all [64][64]: K hi/lo linear; VtS swizzled t^(d&56); Pl swizzled col^((q&7)<<3).
__global__ __launch_bounds__(256) void attn(
    const u16* __restrict__ Qhi, const u16* __restrict__ Qlo,
    const u16* __restrict__ Khi, const u16* __restrict__ Klo,
    const u16* __restrict__ V, const u64* __restrict__ MB,
    u16* __restrict__ X)
{
  __shared__ __align__(16) u16 KhiS[64][64];
  __shared__ __align__(16) u16 KloS[64][64];
  __shared__ __align__(16) u16 VtS[64][64];
  __shared__ __align__(16) u16 Pl[64][64];
  const int b = blockIdx.z, h = blockIdx.y, q0 = blockIdx.x * 64;
  const int tid = threadIdx.x, w = tid >> 6, l = tid & 63;
  const int row = l & 15, kq = (l >> 4) * 8;

  const size_t qbase = ((size_t)(b * SS) + q0 + w * 16 + row) * EE + h * DKK;
  short8 qh[2], ql[2];
  #pragma unroll
  for (int ks = 0; ks < 2; ++ks) {
    qh[ks] = *(const short8*)&Qhi[qbase + ks * 32 + kq];
    ql[ks] = *(const short8*)&Qlo[qbase + ks * 32 + kq];
  }

  float mrow[4], lrow[4];
  f32x4 acco[4];
  #pragma unroll
  for (int r = 0; r < 4; ++r) { mrow[r] = -INFINITY; lrow[r] = 0.f; }
  #pragma unroll
  for (int f = 0; f < 4; ++f) acco[f] = (f32x4){0.f, 0.f, 0.f, 0.f};

  const int qr0 = q0 + w * 16 + ((l >> 4) << 2);

  for (int t0 = 0; t0 < SS; t0 += 64) {
    __syncthreads();
    #pragma unroll
    for (int i = 0; i < 2; ++i) {            // stage K hi/lo (linear) + V (swizzled transpose)
      int u = tid + i * 256; int r = u >> 3, c0 = (u & 7) * 8;
      size_t g = ((size_t)(b * SS) + t0 + r) * EE + h * DKK + c0;
      short8 hv = *(const short8*)&Khi[g];
      short8 lv = *(const short8*)&Klo[g];
      short8 vv = *(const short8*)&V[g];
      *(short8*)&KhiS[r][c0] = hv;
      *(short8*)&KloS[r][c0] = lv;
      int tswz = r ^ c0;                     // c0 = bits 3-5 of d for all j<8
      #pragma unroll
      for (int j = 0; j < 8; ++j) VtS[c0 + j][tswz] = (u16)vv[j];
    }
    __syncthreads();

    // mask bits early (L2-hot 2MB)
    u64 wb[4];
    #pragma unroll
    for (int r = 0; r < 4; ++r)
      wb[r] = MB[((size_t)(b * SS) + qr0 + r) * 32 + (t0 >> 6)] >> (l & 15);

    f32x4 sacc[4];
    #pragma unroll
    for (int f = 0; f < 4; ++f) sacc[f] = (f32x4){0.f, 0.f, 0.f, 0.f};
    #pragma unroll
    for (int f = 0; f < 4; ++f)
      #pragma unroll
      for (int ks = 0; ks < 2; ++ks) {
        short8 kh = *(const short8*)&KhiS[f * 16 + row][ks * 32 + kq];
        short8 kl = *(const short8*)&KloS[f * 16 + row][ks * 32 + kq];
        sacc[f] = __builtin_amdgcn_mfma_f32_16x16x32_bf16(qh[ks], kh, sacc[f], 0, 0, 0);
        sacc[f] = __builtin_amdgcn_mfma_f32_16x16x32_bf16(qh[ks], kl, sacc[f], 0, 0, 0);
        sacc[f] = __builtin_amdgcn_mfma_f32_16x16x32_bf16(ql[ks], kh, sacc[f], 0, 0, 0);
      }

    float sval[4][4];
    #pragma unroll
    for (int f = 0; f < 4; ++f)
      #pragma unroll
      for (int r = 0; r < 4; ++r)
        sval[f][r] = ((wb[r] >> (16 * f)) & 1ULL) ? sacc[f][r] : -1e9f;

    #pragma unroll
    for (int r = 0; r < 4; ++r) {
      float mx = fmaxf(fmaxf(sval[0][r], sval[1][r]), fmaxf(sval[2][r], sval[3][r]));
      #pragma unroll
      for (int off = 1; off < 16; off <<= 1) mx = fmaxf(mx, __shfl_xor(mx, off));
      float mnew = fmaxf(mrow[r], mx);
      float alpha = __expf(mrow[r] - mnew);
      float rs = 0.f;
      #pragma unroll
      for (int f = 0; f < 4; ++f) {
        float p = __expf(sval[f][r] - mnew);
        sval[f][r] = p; rs += p;
      }
      #pragma unroll
      for (int off = 1; off < 16; off <<= 1) rs += __shfl_xor(rs, off);
      lrow[r] = lrow[r] * alpha + rs;
      mrow[r] = mnew;
      #pragma unroll
      for (int f = 0; f < 4; ++f) acco[f][r] *= alpha;
    }

    // P -> LDS (per-wave 16-row slice, swizzled col)
    #pragma unroll
    for (int f = 0; f < 4; ++f)
      #pragma unroll
      for (int r = 0; r < 4; ++r) {
        int rr = ((l >> 4) << 2) + r;                     // row within wave slice
        Pl[w * 16 + rr][(f * 16 + (l & 15)) ^ ((rr & 7) << 3)] = f2bf(sval[f][r]);
      }

    #pragma unroll
    for (int f2 = 0; f2 < 4; ++f2) {
      int d = f2 * 16 + row;
      int vswz = d & 56;
      #pragma unroll
      for (int ks = 0; ks < 2; ++ks) {
        short8 p = *(const short8*)&Pl[w * 16 + row][(ks * 32 + kq) ^ ((row & 7) << 3)];
        short8 vvf = *(const short8*)&VtS[d][(ks * 32 + kq) ^ vswz];
        acco[f2] = __builtin_amdgcn_mfma_f32_16x16x32_bf16(p, vvf, acco[f2], 0, 0, 0);
      }
    }
  }

  // X[b][h*256 + q>>3][(q&7)*64 + d]  (reference reshape quirk)
  #pragma unroll
  for (int f2 = 0; f2 < 4; ++f2)
    #pragma unroll
    for (int r = 0; r < 4; ++r) {
      int q = q0 + w * 16 + ((l >> 4) << 2) + r;
      int d = f2 * 16 + (l & 15);
      float o = acco[f2][r] / lrow[r];
      int sp = h * 256 + (q >> 3);
      int ep = ((q & 7) << 6) + d;
      X[((size_t)(b * SS) + sp) * EE + ep] = f2bf(o);
    }
}

extern "C" void kernel_launch(void* const* d_in, const int* in_sizes, int n_in,
                              void* d_out, int out_size, void* d_ws, size_t ws_size,
                              hipStream_t stream) {
  const float* query  = (const float*)d_in[0];
  const float* key_in = (const float*)d_in[1];
  const float* value  = (const float*)d_in[2];
  const int*   mask   = (const int*)d_in[3];
  const float* Wq = (const float*)d_in[4];
  const float* bq = (const float*)d_in[5];
  const float* Wk = (const float*)d_in[6];
  const float* bk = (const float*)d_in[7];
  const float* Wv = (const float*)d_in[8];
  const float* bv = (const float*)d_in[9];
  const float* Wo = (const float*)d_in[10];
  const float* bo = (const float*)d_in[11];

  u16* ws = (u16*)d_ws;
  const size_t NE = (size_t)MM * EE;
  u16* Qhi = ws;
  u16* Qlo = ws + NE;
  u16* Khi = ws + 2 * NE;
  u16* Klo = ws + 3 * NE;
  u16* Vp  = ws + 4 * NE;
  u16* X   = ws + 5 * NE;
  u64* MBb = (u64*)(ws + 6 * NE);   // [B*S][32] u64 = 2 MB

  dim3 gblk(MM / 128, EE / 64);
  maskpack<<<MM, 256, 0, stream>>>(mask, MBb);
  proj<1><<<gblk, 256, 0, stream>>>(query,  Wq, bq, Qhi, Qlo, 8.0f);  // fold *sqrt(dk)=8 into Q
  proj<1><<<gblk, 256, 0, stream>>>(key_in, Wk, bk, Khi, Klo, 1.0f);
  proj<0><<<gblk, 256, 0, stream>>>(value,  Wv, bv, Vp, nullptr, 1.0f);
  attn<<<dim3(SS / 64, HH, BB), 256, 0, stream>>>(Qhi, Qlo, Khi, Klo, Vp, MBb, X);
  gemm_out<<<gblk, 256, 0, stream>>>(X, Wo, bo, (float*)d_out);
}

// Round 13
// 394.143 us; speedup vs baseline: 1.2862x; 1.1103x over previous
//
#include <hip/hip_runtime.h>

#define BB 4
#define SS 2048
#define EE 512
#define HH 8
#define DKK 64
#define MM (BB*SS)

typedef unsigned short u16;
typedef unsigned int u32;
typedef unsigned long long u64;
typedef __attribute__((ext_vector_type(8))) short short8;
typedef __attribute__((ext_vector_type(4))) short short4v;
typedef __attribute__((ext_vector_type(4))) float f32x4;

__device__ inline u16 f2bf(float f) {            // RNE f32 -> bf16
  union { float f; u32 u; } v; v.f = f;
  u32 r = v.u + 0x7fff + ((v.u >> 16) & 1);
  return (u16)(r >> 16);
}
__device__ inline float bf2f(u16 u) {
  union { u32 u; float f; } v; v.u = ((u32)u) << 16;
  return v.f;
}
__device__ inline void split2(float f, u16 &h, u16 &l) {
  h = f2bf(f);
  l = f2bf(f - bf2f(h));
}

// DPP row-rotate (within 16-lane rows), VALU-speed cross-lane for reductions.
template<int CTRL>
__device__ inline float fdpp(float x) {
  return __builtin_bit_cast(float,
      __builtin_amdgcn_update_dpp(0, __builtin_bit_cast(int, x), CTRL, 0xf, 0xf, true));
}
__device__ inline float rmax16(float x) {        // max over each 16-lane row
  x = fmaxf(x, fdpp<0x121>(x));                  // row_ror:1
  x = fmaxf(x, fdpp<0x122>(x));                  // row_ror:2
  x = fmaxf(x, fdpp<0x124>(x));                  // row_ror:4
  x = fmaxf(x, fdpp<0x128>(x));                  // row_ror:8
  return x;
}
__device__ inline float rsum16(float x) {
  x += fdpp<0x121>(x);
  x += fdpp<0x122>(x);
  x += fdpp<0x124>(x);
  x += fdpp<0x128>(x);
  return x;
}

// ---------- mask [B,S,S] int32 -> bitmask [B*S][32] u64 ----------
__global__ __launch_bounds__(256) void maskpack(const int* __restrict__ mask,
                                                u64* __restrict__ mb) {
  const int bq = blockIdx.x;
  const int w = threadIdx.x >> 6, l = threadIdx.x & 63;
  const int* src = mask + (size_t)bq * SS;
  #pragma unroll
  for (int it = 0; it < 8; ++it) {
    int tb = it * 4 + w;
    int m = src[tb * 64 + l];
    u64 bits = __ballot(m != 0);
    if (l == 0) mb[(size_t)bq * 32 + tb] = bits;
  }
}

// ---------- Projection GEMM (unchanged from round 4) ----------
template<int COMP>
__global__ __launch_bounds__(256) void proj(
    const float* __restrict__ A, const float* __restrict__ W,
    const float* __restrict__ bias, u16* __restrict__ Chi, u16* __restrict__ Clo,
    float cscale)
{
  __shared__ __align__(16) u16 Ah[128][72];
  __shared__ __align__(16) u16 Al[COMP ? 128 : 1][72];
  __shared__ __align__(16) u16 Bh[64][72];
  __shared__ __align__(16) u16 Bl[COMP ? 64 : 1][72];
  const int m0 = blockIdx.x * 128, n0 = blockIdx.y * 64;
  const int tid = threadIdx.x, w = tid >> 6, l = tid & 63;
  const int row = l & 15, kq = (l >> 4) * 8;
  f32x4 acc[2][4];
  #pragma unroll
  for (int i = 0; i < 2; ++i)
    #pragma unroll
    for (int j = 0; j < 4; ++j) acc[i][j] = (f32x4){0.f, 0.f, 0.f, 0.f};

  for (int k0 = 0; k0 < 512; k0 += 64) {
    __syncthreads();
    #pragma unroll
    for (int i = 0; i < 8; ++i) {
      int u = tid + i * 256; int r = u >> 4, c4 = (u & 15) * 4;
      f32x4 v = *(const f32x4*)&A[(size_t)(m0 + r) * 512 + k0 + c4];
      u16 h[4], lo[4];
      #pragma unroll
      for (int j = 0; j < 4; ++j) split2(v[j], h[j], lo[j]);
      *(short4v*)&Ah[r][c4] = (short4v){(short)h[0], (short)h[1], (short)h[2], (short)h[3]};
      if (COMP)
        *(short4v*)&Al[r][c4] = (short4v){(short)lo[0], (short)lo[1], (short)lo[2], (short)lo[3]};
    }
    #pragma unroll
    for (int i = 0; i < 4; ++i) {
      int u = tid + i * 256; int r = u >> 4, c4 = (u & 15) * 4;
      f32x4 v = *(const f32x4*)&W[(size_t)(n0 + r) * 512 + k0 + c4];
      u16 h[4], lo[4];
      #pragma unroll
      for (int j = 0; j < 4; ++j) split2(v[j], h[j], lo[j]);
      *(short4v*)&Bh[r][c4] = (short4v){(short)h[0], (short)h[1], (short)h[2], (short)h[3]};
      if (COMP)
        *(short4v*)&Bl[r][c4] = (short4v){(short)lo[0], (short)lo[1], (short)lo[2], (short)lo[3]};
    }
    __syncthreads();
    short8 ah[2][2], al[2][2], bh[4][2], bl[4][2];
    #pragma unroll
    for (int mf = 0; mf < 2; ++mf)
      #pragma unroll
      for (int ks = 0; ks < 2; ++ks) {
        ah[mf][ks] = *(const short8*)&Ah[w * 32 + mf * 16 + row][ks * 32 + kq];
        if (COMP) al[mf][ks] = *(const short8*)&Al[w * 32 + mf * 16 + row][ks * 32 + kq];
      }
    #pragma unroll
    for (int nf = 0; nf < 4; ++nf)
      #pragma unroll
      for (int ks = 0; ks < 2; ++ks) {
        bh[nf][ks] = *(const short8*)&Bh[nf * 16 + row][ks * 32 + kq];
        if (COMP) bl[nf][ks] = *(const short8*)&Bl[nf * 16 + row][ks * 32 + kq];
      }
    #pragma unroll
    for (int mf = 0; mf < 2; ++mf)
      #pragma unroll
      for (int nf = 0; nf < 4; ++nf)
        #pragma unroll
        for (int ks = 0; ks < 2; ++ks) {
          acc[mf][nf] = __builtin_amdgcn_mfma_f32_16x16x32_bf16(
              ah[mf][ks], bh[nf][ks], acc[mf][nf], 0, 0, 0);
          if (COMP) {
            acc[mf][nf] = __builtin_amdgcn_mfma_f32_16x16x32_bf16(
                ah[mf][ks], bl[nf][ks], acc[mf][nf], 0, 0, 0);
            acc[mf][nf] = __builtin_amdgcn_mfma_f32_16x16x32_bf16(
                al[mf][ks], bh[nf][ks], acc[mf][nf], 0, 0, 0);
          }
        }
  }
  #pragma unroll
  for (int mf = 0; mf < 2; ++mf)
    #pragma unroll
    for (int nf = 0; nf < 4; ++nf)
      #pragma unroll
      for (int r = 0; r < 4; ++r) {
        int m = m0 + w * 32 + mf * 16 + ((l >> 4) << 2) + r;
        int n = n0 + nf * 16 + (l & 15);
        float c = (acc[mf][nf][r] + bias[n]) * cscale;
        size_t idx = (size_t)m * 512 + n;
        if (COMP) { u16 h, lo; split2(c, h, lo); Chi[idx] = h; Clo[idx] = lo; }
        else Chi[idx] = f2bf(c);
      }
}

// ---------- Output GEMM (unchanged) ----------
__global__ __launch_bounds__(256) void gemm_out(
    const u16* __restrict__ A, const float* __restrict__ W,
    const float* __restrict__ bias, float* __restrict__ C)
{
  __shared__ __align__(16) u16 As[128][72];
  __shared__ __align__(16) u16 Bs[64][72];
  const int m0 = blockIdx.x * 128, n0 = blockIdx.y * 64;
  const int tid = threadIdx.x, w = tid >> 6, l = tid & 63;
  const int row = l & 15, kq = (l >> 4) * 8;
  f32x4 acc[2][4];
  #pragma unroll
  for (int i = 0; i < 2; ++i)
    #pragma unroll
    for (int j = 0; j < 4; ++j) acc[i][j] = (f32x4){0.f, 0.f, 0.f, 0.f};

  for (int k0 = 0; k0 < 512; k0 += 64) {
    __syncthreads();
    #pragma unroll
    for (int i = 0; i < 4; ++i) {
      int u = tid + i * 256; int r = u >> 3, c = (u & 7) * 8;
      *(short8*)&As[r][c] = *(const short8*)&A[(size_t)(m0 + r) * 512 + k0 + c];
    }
    #pragma unroll
    for (int i = 0; i < 4; ++i) {
      int u = tid + i * 256; int r = u >> 4, c4 = (u & 15) * 4;
      f32x4 v = *(const f32x4*)&W[(size_t)(n0 + r) * 512 + k0 + c4];
      *(short4v*)&Bs[r][c4] = (short4v){(short)f2bf(v[0]), (short)f2bf(v[1]),
                                        (short)f2bf(v[2]), (short)f2bf(v[3])};
    }
    __syncthreads();
    short8 a[2][2], bfr[4][2];
    #pragma unroll
    for (int mf = 0; mf < 2; ++mf)
      #pragma unroll
      for (int ks = 0; ks < 2; ++ks)
        a[mf][ks] = *(const short8*)&As[w * 32 + mf * 16 + row][ks * 32 + kq];
    #pragma unroll
    for (int nf = 0; nf < 4; ++nf)
      #pragma unroll
      for (int ks = 0; ks < 2; ++ks)
        bfr[nf][ks] = *(const short8*)&Bs[nf * 16 + row][ks * 32 + kq];
    #pragma unroll
    for (int mf = 0; mf < 2; ++mf)
      #pragma unroll
      for (int nf = 0; nf < 4; ++nf)
        #pragma unroll
        for (int ks = 0; ks < 2; ++ks)
          acc[mf][nf] = __builtin_amdgcn_mfma_f32_16x16x32_bf16(
              a[mf][ks], bfr[nf][ks], acc[mf][nf], 0, 0, 0);
  }
  #pragma unroll
  for (int mf = 0; mf < 2; ++mf)
    #pragma unroll
    for (int nf = 0; nf < 4; ++nf)
      #pragma unroll
      for (int r = 0; r < 4; ++r) {
        int m = m0 + w * 32 + mf * 16 + ((l >> 4) << 2) + r;
        int n = n0 + nf * 16 + (l & 15);
        C[(size_t)m * 512 + n] = acc[mf][nf][r] + bias[n];
      }
}

// ---------- Flash attention: reg-staged prefetch, verified swizzles, DPP reduce ----------
// Swizzles (u16-elem units, all involutions applied on write AND read):
//   K tiles : col ^= (row&7)<<3          (write/read both bank-uniform)
//   VtS     : col ^= ((d&7)^(d>>3))<<3   (scatter write covers all 64 residues)
//   Pl      : col ^= ((rr&7)^(rr>>3))<<3
__global__ __launch_bounds__(256) void attn(
    const u16* __restrict__ Qhi, const u16* __restrict__ Qlo,
    const u16* __restrict__ Khi, const u16* __restrict__ Klo,
    const u16* __restrict__ V, const u64* __restrict__ MB,
    u16* __restrict__ X)
{
  __shared__ __align__(16) u16 KhiS[64][64];
  __shared__ __align__(16) u16 KloS[64][64];
  __shared__ __align__(16) u16 VtS[64][64];
  __shared__ __align__(16) u16 Pl[64][64];
  const int b = blockIdx.z, h = blockIdx.y, q0 = blockIdx.x * 64;
  const int tid = threadIdx.x, w = tid >> 6, l = tid & 63;
  const int row = l & 15, kq = (l >> 4) * 8;
  const int r0 = tid >> 3;            // staging row (i adds 32)
  const int c0 = (tid & 7) * 8;       // staging col

  const size_t qbase = ((size_t)(b * SS) + q0 + w * 16 + row) * EE + h * DKK;
  short8 qh[2], ql[2];
  #pragma unroll
  for (int ks = 0; ks < 2; ++ks) {
    qh[ks] = *(const short8*)&Qhi[qbase + ks * 32 + kq];
    ql[ks] = *(const short8*)&Qlo[qbase + ks * 32 + kq];
  }

  float mrow[4], lrow[4];
  f32x4 acco[4];
  #pragma unroll
  for (int r = 0; r < 4; ++r) { mrow[r] = -INFINITY; lrow[r] = 0.f; }
  #pragma unroll
  for (int f = 0; f < 4; ++f) acco[f] = (f32x4){0.f, 0.f, 0.f, 0.f};

  const int qr0 = q0 + w * 16 + ((l >> 4) << 2);
  const size_t mbase = ((size_t)(b * SS) + qr0) * 32;

  short8 sh[2], sl[2], sv[2];
  u64 wb[4], wbn[4];

  // ---- prologue: load tile 0 into regs + mask words, write LDS ----
  #pragma unroll
  for (int i = 0; i < 2; ++i) {
    size_t g = ((size_t)(b * SS) + r0 + 32 * i) * EE + h * DKK + c0;
    sh[i] = *(const short8*)&Khi[g];
    sl[i] = *(const short8*)&Klo[g];
    sv[i] = *(const short8*)&V[g];
  }
  #pragma unroll
  for (int r = 0; r < 4; ++r) wb[r] = MB[mbase + r * 32] >> (l & 15);
  #pragma unroll
  for (int i = 0; i < 2; ++i) {
    int rr = r0 + 32 * i;
    int kc = c0 ^ ((rr & 7) << 3);
    *(short8*)&KhiS[rr][kc] = sh[i];
    *(short8*)&KloS[rr][kc] = sl[i];
    #pragma unroll
    for (int j = 0; j < 8; ++j) {
      int d = c0 + j;
      VtS[d][rr ^ (((d & 7) ^ (d >> 3)) << 3)] = (u16)sv[i][j];
    }
  }
  __syncthreads();

  for (int t0 = 0; t0 < SS; t0 += 64) {
    const bool more = (t0 + 64 < SS);
    // ---- issue next-tile global loads early (latency hides under compute) ----
    if (more) {
      #pragma unroll
      for (int i = 0; i < 2; ++i) {
        size_t g = ((size_t)(b * SS) + t0 + 64 + r0 + 32 * i) * EE + h * DKK + c0;
        sh[i] = *(const short8*)&Khi[g];
        sl[i] = *(const short8*)&Klo[g];
        sv[i] = *(const short8*)&V[g];
      }
      #pragma unroll
      for (int r = 0; r < 4; ++r)
        wbn[r] = MB[mbase + r * 32 + ((t0 >> 6) + 1)] >> (l & 15);
    }

    // ---- QK^T (compensated) from LDS ----
    f32x4 sacc[4];
    #pragma unroll
    for (int f = 0; f < 4; ++f) sacc[f] = (f32x4){0.f, 0.f, 0.f, 0.f};
    #pragma unroll
    for (int f = 0; f < 4; ++f) {
      int krow = f * 16 + row;
      int ksw = (krow & 7) << 3;
      #pragma unroll
      for (int ks = 0; ks < 2; ++ks) {
        short8 kh = *(const short8*)&KhiS[krow][(ks * 32 + kq) ^ ksw];
        short8 kl = *(const short8*)&KloS[krow][(ks * 32 + kq) ^ ksw];
        sacc[f] = __builtin_amdgcn_mfma_f32_16x16x32_bf16(qh[ks], kh, sacc[f], 0, 0, 0);
        sacc[f] = __builtin_amdgcn_mfma_f32_16x16x32_bf16(qh[ks], kl, sacc[f], 0, 0, 0);
        sacc[f] = __builtin_amdgcn_mfma_f32_16x16x32_bf16(ql[ks], kh, sacc[f], 0, 0, 0);
      }
    }

    // ---- mask + online softmax (DPP rotate reduce over 16-lane rows) ----
    float sval[4][4];
    #pragma unroll
    for (int f = 0; f < 4; ++f)
      #pragma unroll
      for (int r = 0; r < 4; ++r)
        sval[f][r] = ((wb[r] >> (16 * f)) & 1ULL) ? sacc[f][r] : -1e9f;

    #pragma unroll
    for (int r = 0; r < 4; ++r) {
      float mx = fmaxf(fmaxf(sval[0][r], sval[1][r]), fmaxf(sval[2][r], sval[3][r]));
      mx = rmax16(mx);
      float mnew = fmaxf(mrow[r], mx);
      float alpha = __expf(mrow[r] - mnew);
      float rs = 0.f;
      #pragma unroll
      for (int f = 0; f < 4; ++f) {
        float p = __expf(sval[f][r] - mnew);
        sval[f][r] = p; rs += p;
      }
      rs = rsum16(rs);
      lrow[r] = lrow[r] * alpha + rs;
      mrow[r] = mnew;
      #pragma unroll
      for (int f = 0; f < 4; ++f) acco[f][r] *= alpha;
    }

    // ---- P -> LDS (per-wave slice) ----
    #pragma unroll
    for (int f = 0; f < 4; ++f)
      #pragma unroll
      for (int r = 0; r < 4; ++r) {
        int rr = ((l >> 4) << 2) + r;
        Pl[w * 16 + rr][(f * 16 + (l & 15)) ^ (((rr & 7) ^ (rr >> 3)) << 3)] = f2bf(sval[f][r]);
      }

    // ---- O += P.V ----
    {
      int psw = ((row & 7) ^ (row >> 3)) << 3;
      #pragma unroll
      for (int f2 = 0; f2 < 4; ++f2) {
        int d = f2 * 16 + row;
        int vsw = ((d & 7) ^ (d >> 3)) << 3;
        #pragma unroll
        for (int ks = 0; ks < 2; ++ks) {
          short8 p = *(const short8*)&Pl[w * 16 + row][(ks * 32 + kq) ^ psw];
          short8 vvf = *(const short8*)&VtS[d][(ks * 32 + kq) ^ vsw];
          acco[f2] = __builtin_amdgcn_mfma_f32_16x16x32_bf16(p, vvf, acco[f2], 0, 0, 0);
        }
      }
    }

    __syncthreads();
    // ---- write staged regs -> LDS for next tile ----
    if (more) {
      #pragma unroll
      for (int i = 0; i < 2; ++i) {
        int rr = r0 + 32 * i;
        int kc = c0 ^ ((rr & 7) << 3);
        *(short8*)&KhiS[rr][kc] = sh[i];
        *(short8*)&KloS[rr][kc] = sl[i];
        #pragma unroll
        for (int j = 0; j < 8; ++j) {
          int d = c0 + j;
          VtS[d][rr ^ (((d & 7) ^ (d >> 3)) << 3)] = (u16)sv[i][j];
        }
      }
      #pragma unroll
      for (int r = 0; r < 4; ++r) wb[r] = wbn[r];
    }
    __syncthreads();
  }

  // X[b][h*256 + q>>3][(q&7)*64 + d]  (reference reshape quirk)
  #pragma unroll
  for (int f2 = 0; f2 < 4; ++f2)
    #pragma unroll
    for (int r = 0; r < 4; ++r) {
      int q = q0 + w * 16 + ((l >> 4) << 2) + r;
      int d = f2 * 16 + (l & 15);
      float o = acco[f2][r] / lrow[r];
      int sp = h * 256 + (q >> 3);
      int ep = ((q & 7) << 6) + d;
      X[((size_t)(b * SS) + sp) * EE + ep] = f2bf(o);
    }
}

extern "C" void kernel_launch(void* const* d_in, const int* in_sizes, int n_in,
                              void* d_out, int out_size, void* d_ws, size_t ws_size,
                              hipStream_t stream) {
  const float* query  = (const float*)d_in[0];
  const float* key_in = (const float*)d_in[1];
  const float* value  = (const float*)d_in[2];
  const int*   mask   = (const int*)d_in[3];
  const float* Wq = (const float*)d_in[4];
  const float* bq = (const float*)d_in[5];
  const float* Wk = (const float*)d_in[6];
  const float* bk = (const float*)d_in[7];
  const float* Wv = (const float*)d_in[8];
  const float* bv = (const float*)d_in[9];
  const float* Wo = (const float*)d_in[10];
  const float* bo = (const float*)d_in[11];

  u16* ws = (u16*)d_ws;
  const size_t NE = (size_t)MM * EE;
  u16* Qhi = ws;
  u16* Qlo = ws + NE;
  u16* Khi = ws + 2 * NE;
  u16* Klo = ws + 3 * NE;
  u16* Vp  = ws + 4 * NE;
  u16* X   = ws + 5 * NE;
  u64* MBb = (u64*)(ws + 6 * NE);   // [B*S][32] u64 = 2 MB

  dim3 gblk(MM / 128, EE / 64);
  maskpack<<<MM, 256, 0, stream>>>(mask, MBb);
  proj<1><<<gblk, 256, 0, stream>>>(query,  Wq, bq, Qhi, Qlo, 8.0f);
  proj<1><<<gblk, 256, 0, stream>>>(key_in, Wk, bk, Khi, Klo, 1.0f);
  proj<0><<<gblk, 256, 0, stream>>>(value,  Wv, bv, Vp, nullptr, 1.0f);
  attn<<<dim3(SS / 64, HH, BB), 256, 0, stream>>>(Qhi, Qlo, Khi, Klo, Vp, MBb, X);
  gemm_out<<<gblk, 256, 0, stream>>>(X, Wo, bo, (float*)d_out);
}